// Round 21
// baseline (148.906 us; speedup 1.0000x reference)
//
#include <hip/hip_runtime.h>
#include <hip/hip_bf16.h>

#define BATCH 65536
#define DIN   128
#define DH    512
#define DOUT  128
#define ROWS  32

typedef __attribute__((ext_vector_type(4))) float f32x4;
typedef __attribute__((ext_vector_type(8))) short s16x8;

__device__ __forceinline__ ushort f32_to_bf16_rn(float f) {
    uint32_t u = __float_as_uint(f);
    uint32_t r = (u + 0x7FFFu + ((u >> 16) & 1u)) >> 16;
    return (ushort)r;
}
__device__ __forceinline__ float bf16_to_f32(ushort h) {
    return __uint_as_float(((uint32_t)h) << 16);
}
__device__ __forceinline__ f32x4 mfma16(s16x8 a, s16x8 b, f32x4 c) {
    return __builtin_amdgcn_mfma_f32_16x16x32_bf16(a, b, c, 0, 0, 0);
}
// two f32x4 -> one s16x8 (plain bf16 RN; tolerance 8.0 >> bf16 GEMM error)
__device__ __forceinline__ s16x8 cvt8(f32x4 v0, f32x4 v1) {
    s16x8 r;
#pragma unroll
    for (int j = 0; j < 4; ++j) r[j] = (short)f32_to_bf16_rn(v0[j]);
#pragma unroll
    for (int j = 0; j < 4; ++j) r[4 + j] = (short)f32_to_bf16_rn(v1[j]);
    return r;
}

// ---------------------------------------------------------------------------
// prep: blk0 softmax(a); blk1..64 split B,C -> bf16 frag-linear. [verified]
// perm[(f*64+lane)*8+j] = M[k][col], k = ks*32+(lane>>4)*8+j,
// col = cg*16+(lane&15). B: f=cg*4+ks (cg<32). C: f=cg*16+ksg (cg<8,ksg<16).
// ---------------------------------------------------------------------------
__global__ void prep_kernel(const float* __restrict__ a,
                            const float* __restrict__ b,
                            const float* __restrict__ c,
                            float* __restrict__ decay,
                            ushort* __restrict__ bhi,
                            ushort* __restrict__ chi)
{
    const int t = threadIdx.x;
    if (blockIdx.x == 0) {
        __shared__ float red[256];
        float v0 = a[t], v1 = a[t + 256];
        red[t] = fmaxf(v0, v1);
        __syncthreads();
        for (int s = 128; s > 0; s >>= 1) {
            if (t < s) red[t] = fmaxf(red[t], red[t + s]);
            __syncthreads();
        }
        float M = red[0];
        __syncthreads();
        float e0 = expf(v0 - M), e1 = expf(v1 - M);
        red[t] = e0 + e1;
        __syncthreads();
        for (int s = 128; s > 0; s >>= 1) {
            if (t < s) red[t] += red[t + s];
            __syncthreads();
        }
        float S = red[0];
        decay[t]       = e0 / S;
        decay[t + 256] = e1 / S;
    } else {
        const int p = (blockIdx.x - 1) * 256 + t;
        const int mtx = p >> 13;
        const int q = p & 8191;
        const int f = q >> 6;
        const int l = q & 63;
        s16x8 hi;
        if (mtx == 0) {
            const int cg = f >> 2, ks = f & 3;
            const int col = cg * 16 + (l & 15);
            const int kbase = ks * 32 + (l >> 4) * 8;
#pragma unroll
            for (int j = 0; j < 8; ++j)
                hi[j] = (short)f32_to_bf16_rn(b[(size_t)(kbase + j) * DH + col]);
            *(s16x8*)(bhi + (size_t)q * 8) = hi;
        } else {
            const int cg = f >> 4, ks = f & 15;
            const int col = cg * 16 + (l & 15);
            const int kbase = ks * 32 + (l >> 4) * 8;
#pragma unroll
            for (int j = 0; j < 8; ++j)
                hi[j] = (short)f32_to_bf16_rn(c[(size_t)(kbase + j) * DOUT + col]);
            *(s16x8*)(chi + (size_t)q * 8) = hi;
        }
    }
}

// ---------------------------------------------------------------------------
// fused v16: v15 EXCEPT bFn/xvn prefetch issue HOISTED to the iteration
// top. Rationale: the per-chunk __syncthreads drains vmcnt(0) including
// the ct+1 prefetches; v15 issued them ~100cy before the barrier -> each
// chunk stalled the full residual load latency. At the top they get
// cF-issue + GEMM1 + X-write (~500-700cy) of cover before the drain.
// Everything else identical to v15 (100.7 us best): block 32 rows, 4
// waves, 8 chunks x 64 cols; LDS 16KB (A 8KB + X dbuf 2x4KB); GEMM1 from
// bF regs; X[ct&1]<-bf16; one barrier/chunk; xn store post-barrier;
// GEMM2 from cF regs.
// ---------------------------------------------------------------------------
__global__ __launch_bounds__(256, 4)
void rnn_fused(const float* __restrict__ u, const float* __restrict__ x,
               const float* __restrict__ decay,
               const ushort* __restrict__ bhi, const ushort* __restrict__ chi,
               float* __restrict__ xn, float* __restrict__ out)
{
    __shared__ __align__(16) char smem[16384];
    ushort* Ah = (ushort*)smem;             // [32][128] bf16, swz, 8KB

    const int t = threadIdx.x;
    const int lane = t & 63, wc = t >> 6;
    const int cl = lane & 15, hk = lane >> 4;
    const int row0 = blockIdx.x * ROWS;

    {   // stage A: u[32][128] f32 -> bf16 swizzled; 64B/thread coalesced
        const int r = t >> 3;
        const int kb = (t & 7) * 2;
#pragma unroll
        for (int i = 0; i < 2; ++i) {
            const float* src = u + (size_t)(row0 + r) * DIN + (kb + i) * 8;
            f32x4 v0 = *(const f32x4*)src;
            f32x4 v1 = *(const f32x4*)(src + 4);
            const int byte = (r * 256 + (kb + i) * 16) ^ ((r & 7) << 4);
            *(s16x8*)((char*)Ah + byte) = cvt8(v0, v1);
        }
    }

    // prologue: bF = B(0) frags; xv = x(0); dvc = decay(0)   (batched issue)
    s16x8 bF[4], bFn[4];
#pragma unroll
    for (int ks = 0; ks < 4; ++ks)
        bF[ks] = *(const s16x8*)(bhi + (size_t)(wc * 4 + ks) * 512 + lane * 8);

    float xv[2][4], xvn[2][4], dvc, dvn;
    dvc = decay[wc * 16 + cl];
#pragma unroll
    for (int mf = 0; mf < 2; ++mf)
#pragma unroll
        for (int j = 0; j < 4; ++j)
            xv[mf][j] = x[(size_t)(row0 + mf * 16 + 4 * hk + j) * DH + wc * 16 + cl];

    __syncthreads();   // A visible

    f32x4 acc2[2][2];
#pragma unroll
    for (int mf = 0; mf < 2; ++mf)
#pragma unroll
        for (int nf = 0; nf < 2; ++nf)
            acc2[mf][nf] = (f32x4){0.f, 0.f, 0.f, 0.f};

    for (int ct = 0; ct < 8; ++ct) {
        char* Xh = smem + 8192 + (ct & 1) * 4096;   // [32][64] bf16, swz

        // ---- issue ALL of this iteration's VMEM at the top:
        //      B(ct+1) + x(ct+1)  (drained by this chunk's barrier -> give
        //      them the whole GEMM1+Xwrite span to land)
        if (ct < 7) {
#pragma unroll
            for (int ks = 0; ks < 4; ++ks)
                bFn[ks] = *(const s16x8*)(bhi +
                    (size_t)(((ct + 1) * 4 + wc) * 4 + ks) * 512 + lane * 8);
            const int ncol = (ct + 1) * 64 + wc * 16 + cl;
            dvn = decay[ncol];
#pragma unroll
            for (int mf = 0; mf < 2; ++mf)
#pragma unroll
                for (int j = 0; j < 4; ++j)
                    xvn[mf][j] = x[(size_t)(row0 + mf * 16 + 4 * hk + j) * DH + ncol];
        }
        //      C(ct) frags (consumed by GEMM2 after the barrier)
        s16x8 cF[2][2];
#pragma unroll
        for (int ks2 = 0; ks2 < 2; ++ks2)
#pragma unroll
            for (int nf = 0; nf < 2; ++nf)
                cF[ks2][nf] = *(const s16x8*)(chi +
                    (size_t)((wc * 2 + nf) * 16 + ct * 2 + ks2) * 512 + lane * 8);

        // ---- GEMM1: acc1 = u @ B-chunk from bF regs (LDS A + MFMA only)
        f32x4 acc1[2];
        acc1[0] = (f32x4){0.f, 0.f, 0.f, 0.f};
        acc1[1] = (f32x4){0.f, 0.f, 0.f, 0.f};
#pragma unroll
        for (int ks = 0; ks < 4; ++ks) {
            const int ko = ks * 32 + hk * 8;
            s16x8 ah[2];
#pragma unroll
            for (int mf = 0; mf < 2; ++mf) {
                const int r = mf * 16 + cl;
                const int byte = (r * 256 + ko * 2) ^ ((r & 7) << 4);
                ah[mf] = *(const s16x8*)((const char*)Ah + byte);
            }
#pragma unroll
            for (int mf = 0; mf < 2; ++mf) acc1[mf] = mfma16(ah[mf], bF[ks], acc1[mf]);
        }

        // ---- X[ct&1] <- bf16(acc1 + dv*x) (LDS only; xn store deferred)
        {
#pragma unroll
            for (int mf = 0; mf < 2; ++mf) {
#pragma unroll
                for (int j = 0; j < 4; ++j) {
                    const int rl = mf * 16 + 4 * hk + j;
                    const float v = acc1[mf][j] + dvc * xv[mf][j];
                    const int cbyte = (rl * 128 + (wc * 16 + cl) * 2) ^ ((rl & 7) << 4);
                    *(ushort*)(Xh + cbyte) = f32_to_bf16_rn(v);
                }
            }
        }

        __syncthreads();   // single barrier: X[ct&1] visible to all waves

        // ---- xn store AFTER the barrier: retires during GEMM2 + next chunk
        {
            const int col = ct * 64 + wc * 16 + cl;
#pragma unroll
            for (int mf = 0; mf < 2; ++mf)
#pragma unroll
                for (int j = 0; j < 4; ++j)
                    xn[(size_t)(row0 + mf * 16 + 4 * hk + j) * DH + col] =
                        acc1[mf][j] + dvc * xv[mf][j];
        }

        // ---- GEMM2: acc2 += X @ C-chunk from cF regs
#pragma unroll
        for (int ks2 = 0; ks2 < 2; ++ks2) {
            const int ko = ks2 * 32 + hk * 8;
            s16x8 ah2[2];
#pragma unroll
            for (int mf = 0; mf < 2; ++mf) {
                const int r = mf * 16 + cl;
                const int byte = (r * 128 + ko * 2) ^ ((r & 7) << 4);
                ah2[mf] = *(const s16x8*)((const char*)Xh + byte);
            }
#pragma unroll
            for (int nf = 0; nf < 2; ++nf)
#pragma unroll
                for (int mf = 0; mf < 2; ++mf)
                    acc2[mf][nf] = mfma16(ah2[mf], cF[ks2][nf], acc2[mf][nf]);
        }

        // ---- rotate prefetched state
#pragma unroll
        for (int ks = 0; ks < 4; ++ks) bF[ks] = bFn[ks];
        dvc = dvn;
#pragma unroll
        for (int mf = 0; mf < 2; ++mf)
#pragma unroll
            for (int j = 0; j < 4; ++j) xv[mf][j] = xvn[mf][j];
    }

    // ---- final: store out[32 x 128]; wave covers cols [wc*32, +32)
#pragma unroll
    for (int nf = 0; nf < 2; ++nf) {
        const int ocol = wc * 32 + nf * 16 + cl;
#pragma unroll
        for (int mf = 0; mf < 2; ++mf) {
#pragma unroll
            for (int j = 0; j < 4; ++j) {
                const int rl = mf * 16 + 4 * hk + j;
                out[(size_t)(row0 + rl) * DOUT + ocol] = acc2[mf][nf][j];
            }
        }
    }
}

extern "C" void kernel_launch(void* const* d_in, const int* in_sizes, int n_in,
                              void* d_out, int out_size, void* d_ws, size_t ws_size,
                              hipStream_t stream)
{
    const float* x = (const float*)d_in[0];
    const float* u = (const float*)d_in[1];
    const float* a = (const float*)d_in[2];
    const float* b = (const float*)d_in[3];
    const float* c = (const float*)d_in[4];

    float* xn  = (float*)d_out;                       // [BATCH][DH]
    float* out = xn + (size_t)BATCH * DH;             // [BATCH][DOUT]

    char* ws = (char*)d_ws;
    float*  decay = (float*)ws;                       // 512 f32
    ushort* bhi = (ushort*)(ws + 4096);               // 128KB frag-linear B
    ushort* chi = bhi + 128 * 512;                    // 128KB frag-linear C

    prep_kernel<<<dim3(65), dim3(256), 0, stream>>>(a, b, c, decay, bhi, chi);
    rnn_fused<<<dim3(BATCH / ROWS), dim3(256), 0, stream>>>(u, x, decay, bhi, chi, xn, out);
}

// Round 22
// 100.970 us; speedup vs baseline: 1.4748x; 1.4748x over previous
//
#include <hip/hip_runtime.h>
#include <hip/hip_bf16.h>

#define BATCH 65536
#define DIN   128
#define DH    512
#define DOUT  128
#define ROWS  32

typedef __attribute__((ext_vector_type(4))) float f32x4;
typedef __attribute__((ext_vector_type(8))) short s16x8;

__device__ __forceinline__ ushort f32_to_bf16_rn(float f) {
    uint32_t u = __float_as_uint(f);
    uint32_t r = (u + 0x7FFFu + ((u >> 16) & 1u)) >> 16;
    return (ushort)r;
}
__device__ __forceinline__ float bf16_to_f32(ushort h) {
    return __uint_as_float(((uint32_t)h) << 16);
}
__device__ __forceinline__ f32x4 mfma16(s16x8 a, s16x8 b, f32x4 c) {
    return __builtin_amdgcn_mfma_f32_16x16x32_bf16(a, b, c, 0, 0, 0);
}
// two f32x4 -> one s16x8 (plain bf16 RN; tolerance 8.0 >> bf16 GEMM error)
__device__ __forceinline__ s16x8 cvt8(f32x4 v0, f32x4 v1) {
    s16x8 r;
#pragma unroll
    for (int j = 0; j < 4; ++j) r[j] = (short)f32_to_bf16_rn(v0[j]);
#pragma unroll
    for (int j = 0; j < 4; ++j) r[4 + j] = (short)f32_to_bf16_rn(v1[j]);
    return r;
}

// ---------------------------------------------------------------------------
// prep: blk0 softmax(a); blk1..64 split B,C -> bf16 frag-linear. [verified]
// perm[(f*64+lane)*8+j] = M[k][col], k = ks*32+(lane>>4)*8+j,
// col = cg*16+(lane&15). B: f=cg*4+ks (cg<32). C: f=cg*16+ksg (cg<8,ksg<16).
// ---------------------------------------------------------------------------
__global__ void prep_kernel(const float* __restrict__ a,
                            const float* __restrict__ b,
                            const float* __restrict__ c,
                            float* __restrict__ decay,
                            ushort* __restrict__ bhi,
                            ushort* __restrict__ chi)
{
    const int t = threadIdx.x;
    if (blockIdx.x == 0) {
        __shared__ float red[256];
        float v0 = a[t], v1 = a[t + 256];
        red[t] = fmaxf(v0, v1);
        __syncthreads();
        for (int s = 128; s > 0; s >>= 1) {
            if (t < s) red[t] = fmaxf(red[t], red[t + s]);
            __syncthreads();
        }
        float M = red[0];
        __syncthreads();
        float e0 = expf(v0 - M), e1 = expf(v1 - M);
        red[t] = e0 + e1;
        __syncthreads();
        for (int s = 128; s > 0; s >>= 1) {
            if (t < s) red[t] += red[t + s];
            __syncthreads();
        }
        float S = red[0];
        decay[t]       = e0 / S;
        decay[t + 256] = e1 / S;
    } else {
        const int p = (blockIdx.x - 1) * 256 + t;
        const int mtx = p >> 13;
        const int q = p & 8191;
        const int f = q >> 6;
        const int l = q & 63;
        s16x8 hi;
        if (mtx == 0) {
            const int cg = f >> 2, ks = f & 3;
            const int col = cg * 16 + (l & 15);
            const int kbase = ks * 32 + (l >> 4) * 8;
#pragma unroll
            for (int j = 0; j < 8; ++j)
                hi[j] = (short)f32_to_bf16_rn(b[(size_t)(kbase + j) * DH + col]);
            *(s16x8*)(bhi + (size_t)q * 8) = hi;
        } else {
            const int cg = f >> 4, ks = f & 15;
            const int col = cg * 16 + (l & 15);
            const int kbase = ks * 32 + (l >> 4) * 8;
#pragma unroll
            for (int j = 0; j < 8; ++j)
                hi[j] = (short)f32_to_bf16_rn(c[(size_t)(kbase + j) * DOUT + col]);
            *(s16x8*)(chi + (size_t)q * 8) = hi;
        }
    }
}

// ---------------------------------------------------------------------------
// fused v15 (FINAL, reverted from v16 regression): best measured 100.7us.
// Block 32 rows, 4 waves, 8 chunks x 64 cols; LDS 16KB (A 8KB + X dbuf
// 2x4KB); VGPR 64, no spill. Per chunk:
//   cF = C(ct) frags issued first (covered by GEMM1 + X-write);
//   GEMM1 u@B from bF regs (LDS A + MFMA only);
//   B(ct+1) + x(ct+1) issued LATE (short live ranges -- v16's hoist
//     spilled; this placement is load-bearing);
//   X[ct&1] <- bf16(acc1 + dv*x) (LDS only);
//   ONE __syncthreads (X visible);
//   xn store AFTER the barrier (retires under GEMM2 + next chunk --
//     pre-barrier placement costs ~3us to the vmcnt(0) drain);
//   GEMM2 X@C from cF regs.
// ---------------------------------------------------------------------------
__global__ __launch_bounds__(256, 4)
void rnn_fused(const float* __restrict__ u, const float* __restrict__ x,
               const float* __restrict__ decay,
               const ushort* __restrict__ bhi, const ushort* __restrict__ chi,
               float* __restrict__ xn, float* __restrict__ out)
{
    __shared__ __align__(16) char smem[16384];
    ushort* Ah = (ushort*)smem;             // [32][128] bf16, swz, 8KB

    const int t = threadIdx.x;
    const int lane = t & 63, wc = t >> 6;
    const int cl = lane & 15, hk = lane >> 4;
    const int row0 = blockIdx.x * ROWS;

    {   // stage A: u[32][128] f32 -> bf16 swizzled; 64B/thread coalesced
        const int r = t >> 3;
        const int kb = (t & 7) * 2;
#pragma unroll
        for (int i = 0; i < 2; ++i) {
            const float* src = u + (size_t)(row0 + r) * DIN + (kb + i) * 8;
            f32x4 v0 = *(const f32x4*)src;
            f32x4 v1 = *(const f32x4*)(src + 4);
            const int byte = (r * 256 + (kb + i) * 16) ^ ((r & 7) << 4);
            *(s16x8*)((char*)Ah + byte) = cvt8(v0, v1);
        }
    }

    // prologue: bF = B(0) frags; xv = x(0); dvc = decay(0)   (batched issue)
    s16x8 bF[4], bFn[4];
#pragma unroll
    for (int ks = 0; ks < 4; ++ks)
        bF[ks] = *(const s16x8*)(bhi + (size_t)(wc * 4 + ks) * 512 + lane * 8);

    float xv[2][4], xvn[2][4], dvc, dvn;
    dvc = decay[wc * 16 + cl];
#pragma unroll
    for (int mf = 0; mf < 2; ++mf)
#pragma unroll
        for (int j = 0; j < 4; ++j)
            xv[mf][j] = x[(size_t)(row0 + mf * 16 + 4 * hk + j) * DH + wc * 16 + cl];

    __syncthreads();   // A visible

    f32x4 acc2[2][2];
#pragma unroll
    for (int mf = 0; mf < 2; ++mf)
#pragma unroll
        for (int nf = 0; nf < 2; ++nf)
            acc2[mf][nf] = (f32x4){0.f, 0.f, 0.f, 0.f};

    for (int ct = 0; ct < 8; ++ct) {
        char* Xh = smem + 8192 + (ct & 1) * 4096;   // [32][64] bf16, swz

        // ---- issue C(ct) frag loads FIRST (consumed at chunk end)
        s16x8 cF[2][2];
#pragma unroll
        for (int ks2 = 0; ks2 < 2; ++ks2)
#pragma unroll
            for (int nf = 0; nf < 2; ++nf)
                cF[ks2][nf] = *(const s16x8*)(chi +
                    (size_t)((wc * 2 + nf) * 16 + ct * 2 + ks2) * 512 + lane * 8);

        // ---- GEMM1: acc1 = u @ B-chunk from bF regs (LDS A + MFMA only)
        f32x4 acc1[2];
        acc1[0] = (f32x4){0.f, 0.f, 0.f, 0.f};
        acc1[1] = (f32x4){0.f, 0.f, 0.f, 0.f};
#pragma unroll
        for (int ks = 0; ks < 4; ++ks) {
            const int ko = ks * 32 + hk * 8;
            s16x8 ah[2];
#pragma unroll
            for (int mf = 0; mf < 2; ++mf) {
                const int r = mf * 16 + cl;
                const int byte = (r * 256 + ko * 2) ^ ((r & 7) << 4);
                ah[mf] = *(const s16x8*)((const char*)Ah + byte);
            }
#pragma unroll
            for (int mf = 0; mf < 2; ++mf) acc1[mf] = mfma16(ah[mf], bF[ks], acc1[mf]);
        }

        // ---- issue B(ct+1) + x(ct+1) (complete during epilogue/barrier)
        if (ct < 7) {
#pragma unroll
            for (int ks = 0; ks < 4; ++ks)
                bFn[ks] = *(const s16x8*)(bhi +
                    (size_t)(((ct + 1) * 4 + wc) * 4 + ks) * 512 + lane * 8);
            const int ncol = (ct + 1) * 64 + wc * 16 + cl;
            dvn = decay[ncol];
#pragma unroll
            for (int mf = 0; mf < 2; ++mf)
#pragma unroll
                for (int j = 0; j < 4; ++j)
                    xvn[mf][j] = x[(size_t)(row0 + mf * 16 + 4 * hk + j) * DH + ncol];
        }

        // ---- X[ct&1] <- bf16(acc1 + dv*x) (LDS only; xn store deferred)
        {
#pragma unroll
            for (int mf = 0; mf < 2; ++mf) {
#pragma unroll
                for (int j = 0; j < 4; ++j) {
                    const int rl = mf * 16 + 4 * hk + j;
                    const float v = acc1[mf][j] + dvc * xv[mf][j];
                    const int cbyte = (rl * 128 + (wc * 16 + cl) * 2) ^ ((rl & 7) << 4);
                    *(ushort*)(Xh + cbyte) = f32_to_bf16_rn(v);
                }
            }
        }

        __syncthreads();   // single barrier: X[ct&1] visible to all waves

        // ---- xn store AFTER the barrier: retires during GEMM2 + next chunk
        {
            const int col = ct * 64 + wc * 16 + cl;
#pragma unroll
            for (int mf = 0; mf < 2; ++mf)
#pragma unroll
                for (int j = 0; j < 4; ++j)
                    xn[(size_t)(row0 + mf * 16 + 4 * hk + j) * DH + col] =
                        acc1[mf][j] + dvc * xv[mf][j];
        }

        // ---- GEMM2: acc2 += X @ C-chunk from cF regs
#pragma unroll
        for (int ks2 = 0; ks2 < 2; ++ks2) {
            const int ko = ks2 * 32 + hk * 8;
            s16x8 ah2[2];
#pragma unroll
            for (int mf = 0; mf < 2; ++mf) {
                const int r = mf * 16 + cl;
                const int byte = (r * 128 + ko * 2) ^ ((r & 7) << 4);
                ah2[mf] = *(const s16x8*)((const char*)Xh + byte);
            }
#pragma unroll
            for (int nf = 0; nf < 2; ++nf)
#pragma unroll
                for (int mf = 0; mf < 2; ++mf)
                    acc2[mf][nf] = mfma16(ah2[mf], cF[ks2][nf], acc2[mf][nf]);
        }

        // ---- rotate prefetched state
#pragma unroll
        for (int ks = 0; ks < 4; ++ks) bF[ks] = bFn[ks];
        dvc = dvn;
#pragma unroll
        for (int mf = 0; mf < 2; ++mf)
#pragma unroll
            for (int j = 0; j < 4; ++j) xv[mf][j] = xvn[mf][j];
    }

    // ---- final: store out[32 x 128]; wave covers cols [wc*32, +32)
#pragma unroll
    for (int nf = 0; nf < 2; ++nf) {
        const int ocol = wc * 32 + nf * 16 + cl;
#pragma unroll
        for (int mf = 0; mf < 2; ++mf) {
#pragma unroll
            for (int j = 0; j < 4; ++j) {
                const int rl = mf * 16 + 4 * hk + j;
                out[(size_t)(row0 + rl) * DOUT + ocol] = acc2[mf][nf][j];
            }
        }
    }
}

extern "C" void kernel_launch(void* const* d_in, const int* in_sizes, int n_in,
                              void* d_out, int out_size, void* d_ws, size_t ws_size,
                              hipStream_t stream)
{
    const float* x = (const float*)d_in[0];
    const float* u = (const float*)d_in[1];
    const float* a = (const float*)d_in[2];
    const float* b = (const float*)d_in[3];
    const float* c = (const float*)d_in[4];

    float* xn  = (float*)d_out;                       // [BATCH][DH]
    float* out = xn + (size_t)BATCH * DH;             // [BATCH][DOUT]

    char* ws = (char*)d_ws;
    float*  decay = (float*)ws;                       // 512 f32
    ushort* bhi = (ushort*)(ws + 4096);               // 128KB frag-linear B
    ushort* chi = bhi + 128 * 512;                    // 128KB frag-linear C

    prep_kernel<<<dim3(65), dim3(256), 0, stream>>>(a, b, c, decay, bhi, chi);
    rnn_fused<<<dim3(BATCH / ROWS), dim3(256), 0, stream>>>(u, x, decay, bhi, chi, xn, out);
}

// Round 23
// 100.484 us; speedup vs baseline: 1.4819x; 1.0048x over previous
//
#include <hip/hip_runtime.h>
#include <hip/hip_bf16.h>

#define BATCH 65536
#define DIN   128
#define DH    512
#define DOUT  128
#define ROWS  32

typedef __attribute__((ext_vector_type(4))) float f32x4;
typedef __attribute__((ext_vector_type(8))) short s16x8;

__device__ __forceinline__ ushort f32_to_bf16_rn(float f) {
    uint32_t u = __float_as_uint(f);
    uint32_t r = (u + 0x7FFFu + ((u >> 16) & 1u)) >> 16;
    return (ushort)r;
}
__device__ __forceinline__ float bf16_to_f32(ushort h) {
    return __uint_as_float(((uint32_t)h) << 16);
}
__device__ __forceinline__ f32x4 mfma16(s16x8 a, s16x8 b, f32x4 c) {
    return __builtin_amdgcn_mfma_f32_16x16x32_bf16(a, b, c, 0, 0, 0);
}
// two f32x4 -> one s16x8 (plain bf16 RN; tolerance 8.0 >> bf16 GEMM error)
__device__ __forceinline__ s16x8 cvt8(f32x4 v0, f32x4 v1) {
    s16x8 r;
#pragma unroll
    for (int j = 0; j < 4; ++j) r[j] = (short)f32_to_bf16_rn(v0[j]);
#pragma unroll
    for (int j = 0; j < 4; ++j) r[4 + j] = (short)f32_to_bf16_rn(v1[j]);
    return r;
}

// lgkm-only barrier: rendezvous + LDS visibility WITHOUT the vmcnt(0)
// drain __syncthreads imposes. Wave lockstep is preserved (so cross-wave
// xn-store line merging survives); in-flight global loads/stores are not.
#define LGKM_BARRIER() \
    asm volatile("s_waitcnt lgkmcnt(0)\n\ts_barrier" ::: "memory")

// ---------------------------------------------------------------------------
// prep: blk0 softmax(a); blk1..64 split B,C -> bf16 frag-linear. [verified]
// perm[(f*64+lane)*8+j] = M[k][col], k = ks*32+(lane>>4)*8+j,
// col = cg*16+(lane&15). B: f=cg*4+ks (cg<32). C: f=cg*16+ksg (cg<8,ksg<16).
// ---------------------------------------------------------------------------
__global__ void prep_kernel(const float* __restrict__ a,
                            const float* __restrict__ b,
                            const float* __restrict__ c,
                            float* __restrict__ decay,
                            ushort* __restrict__ bhi,
                            ushort* __restrict__ chi)
{
    const int t = threadIdx.x;
    if (blockIdx.x == 0) {
        __shared__ float red[256];
        float v0 = a[t], v1 = a[t + 256];
        red[t] = fmaxf(v0, v1);
        __syncthreads();
        for (int s = 128; s > 0; s >>= 1) {
            if (t < s) red[t] = fmaxf(red[t], red[t + s]);
            __syncthreads();
        }
        float M = red[0];
        __syncthreads();
        float e0 = expf(v0 - M), e1 = expf(v1 - M);
        red[t] = e0 + e1;
        __syncthreads();
        for (int s = 128; s > 0; s >>= 1) {
            if (t < s) red[t] += red[t + s];
            __syncthreads();
        }
        float S = red[0];
        decay[t]       = e0 / S;
        decay[t + 256] = e1 / S;
    } else {
        const int p = (blockIdx.x - 1) * 256 + t;
        const int mtx = p >> 13;
        const int q = p & 8191;
        const int f = q >> 6;
        const int l = q & 63;
        s16x8 hi;
        if (mtx == 0) {
            const int cg = f >> 2, ks = f & 3;
            const int col = cg * 16 + (l & 15);
            const int kbase = ks * 32 + (l >> 4) * 8;
#pragma unroll
            for (int j = 0; j < 8; ++j)
                hi[j] = (short)f32_to_bf16_rn(b[(size_t)(kbase + j) * DH + col]);
            *(s16x8*)(bhi + (size_t)q * 8) = hi;
        } else {
            const int cg = f >> 4, ks = f & 15;
            const int col = cg * 16 + (l & 15);
            const int kbase = ks * 32 + (l >> 4) * 8;
#pragma unroll
            for (int j = 0; j < 8; ++j)
                hi[j] = (short)f32_to_bf16_rn(c[(size_t)(kbase + j) * DOUT + col]);
            *(s16x8*)(chi + (size_t)q * 8) = hi;
        }
    }
}

// ---------------------------------------------------------------------------
// fused v17: v15 EXCEPT both __syncthreads -> lgkm-only barrier.
// Rationale: v15's per-chunk __syncthreads drains vmcnt(0) -- killing the
// pre-barrier-issued bFn/xvn/cF residual latency AND the prior chunk's xn
// stores every chunk. lgkm-only keeps the rendezvous (cross-wave xn line
// merging survives: stores still issue in lockstep windows post-barrier)
// and LDS visibility (lgkmcnt(0) covers ds ops; X dbuf WAR separated by
// 2 barriers) while letting VMEM ride across.
// Everything else identical to v15 (100.7us best): block 32 rows, 4
// waves, 8 chunks x 64 cols; LDS 16KB; VGPR 64; cF first; GEMM1 from bF
// regs; B/x(ct+1) late issue; X[ct&1]<-bf16; xn store post-barrier;
// GEMM2 from cF regs.
// ---------------------------------------------------------------------------
__global__ __launch_bounds__(256, 4)
void rnn_fused(const float* __restrict__ u, const float* __restrict__ x,
               const float* __restrict__ decay,
               const ushort* __restrict__ bhi, const ushort* __restrict__ chi,
               float* __restrict__ xn, float* __restrict__ out)
{
    __shared__ __align__(16) char smem[16384];
    ushort* Ah = (ushort*)smem;             // [32][128] bf16, swz, 8KB

    const int t = threadIdx.x;
    const int lane = t & 63, wc = t >> 6;
    const int cl = lane & 15, hk = lane >> 4;
    const int row0 = blockIdx.x * ROWS;

    {   // stage A: u[32][128] f32 -> bf16 swizzled; 64B/thread coalesced
        const int r = t >> 3;
        const int kb = (t & 7) * 2;
#pragma unroll
        for (int i = 0; i < 2; ++i) {
            const float* src = u + (size_t)(row0 + r) * DIN + (kb + i) * 8;
            f32x4 v0 = *(const f32x4*)src;
            f32x4 v1 = *(const f32x4*)(src + 4);
            const int byte = (r * 256 + (kb + i) * 16) ^ ((r & 7) << 4);
            *(s16x8*)((char*)Ah + byte) = cvt8(v0, v1);
        }
    }

    // prologue: bF = B(0) frags; xv = x(0); dvc = decay(0)   (batched issue)
    s16x8 bF[4], bFn[4];
#pragma unroll
    for (int ks = 0; ks < 4; ++ks)
        bF[ks] = *(const s16x8*)(bhi + (size_t)(wc * 4 + ks) * 512 + lane * 8);

    float xv[2][4], xvn[2][4], dvc, dvn;
    dvc = decay[wc * 16 + cl];
#pragma unroll
    for (int mf = 0; mf < 2; ++mf)
#pragma unroll
        for (int j = 0; j < 4; ++j)
            xv[mf][j] = x[(size_t)(row0 + mf * 16 + 4 * hk + j) * DH + wc * 16 + cl];

    LGKM_BARRIER();   // A visible; prologue loads stay in flight

    f32x4 acc2[2][2];
#pragma unroll
    for (int mf = 0; mf < 2; ++mf)
#pragma unroll
        for (int nf = 0; nf < 2; ++nf)
            acc2[mf][nf] = (f32x4){0.f, 0.f, 0.f, 0.f};

    for (int ct = 0; ct < 8; ++ct) {
        char* Xh = smem + 8192 + (ct & 1) * 4096;   // [32][64] bf16, swz

        // ---- issue C(ct) frag loads FIRST (consumed at chunk end)
        s16x8 cF[2][2];
#pragma unroll
        for (int ks2 = 0; ks2 < 2; ++ks2)
#pragma unroll
            for (int nf = 0; nf < 2; ++nf)
                cF[ks2][nf] = *(const s16x8*)(chi +
                    (size_t)((wc * 2 + nf) * 16 + ct * 2 + ks2) * 512 + lane * 8);

        // ---- GEMM1: acc1 = u @ B-chunk from bF regs (LDS A + MFMA only)
        f32x4 acc1[2];
        acc1[0] = (f32x4){0.f, 0.f, 0.f, 0.f};
        acc1[1] = (f32x4){0.f, 0.f, 0.f, 0.f};
#pragma unroll
        for (int ks = 0; ks < 4; ++ks) {
            const int ko = ks * 32 + hk * 8;
            s16x8 ah[2];
#pragma unroll
            for (int mf = 0; mf < 2; ++mf) {
                const int r = mf * 16 + cl;
                const int byte = (r * 256 + ko * 2) ^ ((r & 7) << 4);
                ah[mf] = *(const s16x8*)((const char*)Ah + byte);
            }
#pragma unroll
            for (int mf = 0; mf < 2; ++mf) acc1[mf] = mfma16(ah[mf], bF[ks], acc1[mf]);
        }

        // ---- issue B(ct+1) + x(ct+1) (short live ranges; v16's hoist spilled)
        if (ct < 7) {
#pragma unroll
            for (int ks = 0; ks < 4; ++ks)
                bFn[ks] = *(const s16x8*)(bhi +
                    (size_t)(((ct + 1) * 4 + wc) * 4 + ks) * 512 + lane * 8);
            const int ncol = (ct + 1) * 64 + wc * 16 + cl;
            dvn = decay[ncol];
#pragma unroll
            for (int mf = 0; mf < 2; ++mf)
#pragma unroll
                for (int j = 0; j < 4; ++j)
                    xvn[mf][j] = x[(size_t)(row0 + mf * 16 + 4 * hk + j) * DH + ncol];
        }

        // ---- X[ct&1] <- bf16(acc1 + dv*x) (LDS only; xn store deferred)
        {
#pragma unroll
            for (int mf = 0; mf < 2; ++mf) {
#pragma unroll
                for (int j = 0; j < 4; ++j) {
                    const int rl = mf * 16 + 4 * hk + j;
                    const float v = acc1[mf][j] + dvc * xv[mf][j];
                    const int cbyte = (rl * 128 + (wc * 16 + cl) * 2) ^ ((rl & 7) << 4);
                    *(ushort*)(Xh + cbyte) = f32_to_bf16_rn(v);
                }
            }
        }

        LGKM_BARRIER();   // X[ct&1] visible; VMEM (prefetches, prior xn
                          // stores) stays in flight across

        // ---- xn store AFTER the barrier: retires during GEMM2 + next chunk
        {
            const int col = ct * 64 + wc * 16 + cl;
#pragma unroll
            for (int mf = 0; mf < 2; ++mf)
#pragma unroll
                for (int j = 0; j < 4; ++j)
                    xn[(size_t)(row0 + mf * 16 + 4 * hk + j) * DH + col] =
                        acc1[mf][j] + dvc * xv[mf][j];
        }

        // ---- GEMM2: acc2 += X @ C-chunk from cF regs
#pragma unroll
        for (int ks2 = 0; ks2 < 2; ++ks2) {
            const int ko = ks2 * 32 + hk * 8;
            s16x8 ah2[2];
#pragma unroll
            for (int mf = 0; mf < 2; ++mf) {
                const int r = mf * 16 + cl;
                const int byte = (r * 128 + ko * 2) ^ ((r & 7) << 4);
                ah2[mf] = *(const s16x8*)((const char*)Xh + byte);
            }
#pragma unroll
            for (int nf = 0; nf < 2; ++nf)
#pragma unroll
                for (int mf = 0; mf < 2; ++mf)
                    acc2[mf][nf] = mfma16(ah2[mf], cF[ks2][nf], acc2[mf][nf]);
        }

        // ---- rotate prefetched state
#pragma unroll
        for (int ks = 0; ks < 4; ++ks) bF[ks] = bFn[ks];
        dvc = dvn;
#pragma unroll
        for (int mf = 0; mf < 2; ++mf)
#pragma unroll
            for (int j = 0; j < 4; ++j) xv[mf][j] = xvn[mf][j];
    }

    // ---- final: store out[32 x 128]; wave covers cols [wc*32, +32)
#pragma unroll
    for (int nf = 0; nf < 2; ++nf) {
        const int ocol = wc * 32 + nf * 16 + cl;
#pragma unroll
        for (int mf = 0; mf < 2; ++mf) {
#pragma unroll
            for (int j = 0; j < 4; ++j) {
                const int rl = mf * 16 + 4 * hk + j;
                out[(size_t)(row0 + rl) * DOUT + ocol] = acc2[mf][nf][j];
            }
        }
    }
}

extern "C" void kernel_launch(void* const* d_in, const int* in_sizes, int n_in,
                              void* d_out, int out_size, void* d_ws, size_t ws_size,
                              hipStream_t stream)
{
    const float* x = (const float*)d_in[0];
    const float* u = (const float*)d_in[1];
    const float* a = (const float*)d_in[2];
    const float* b = (const float*)d_in[3];
    const float* c = (const float*)d_in[4];

    float* xn  = (float*)d_out;                       // [BATCH][DH]
    float* out = xn + (size_t)BATCH * DH;             // [BATCH][DOUT]

    char* ws = (char*)d_ws;
    float*  decay = (float*)ws;                       // 512 f32
    ushort* bhi = (ushort*)(ws + 4096);               // 128KB frag-linear B
    ushort* chi = bhi + 128 * 512;                    // 128KB frag-linear C

    prep_kernel<<<dim3(65), dim3(256), 0, stream>>>(a, b, c, decay, bhi, chi);
    rnn_fused<<<dim3(BATCH / ROWS), dim3(256), 0, stream>>>(u, x, decay, bhi, chi, xn, out);
}